// Round 3
// baseline (351.037 us; speedup 1.0000x reference)
//
#include <hip/hip_runtime.h>

typedef __attribute__((ext_vector_type(8))) _Float16 half8;
typedef __attribute__((ext_vector_type(4))) _Float16 half4v;
typedef __attribute__((ext_vector_type(4))) float floatx4;

#define NB 128
#define NN 64
#define NV 14
#define PP 32
#define SS 14
#define HH 128
#define DE 64
#define NCLS 5
#define PITCH 136   // halves; 272 B rows -> 2-way-max bank aliasing (free)

// fragment-major weight offsets (halves). layout: [nt][ks][lane][8]
#define OFF_W2   0
#define OFF_W3   16384
#define OFF_W2PV 24576
#define OFF_W3PV 40960
#define OFF_FO1  49152
#define OFF_FO2  69632
#define OFF_FO3  86016

__device__ __forceinline__ floatx4 MFMA(half8 a, half8 b, floatx4 c) {
  return __builtin_amdgcn_mfma_f32_16x16x32_f16(a, b, c, 0, 0, 0);
}

// ---------------- K0: layer-1 precompute (+bias fold), frag-major weights, d_out zero ----------------
__global__ __launch_bounds__(256) void k0_prep(
    const float* __restrict__ x, const float* __restrict__ y,
    const float* __restrict__ fr1_w, const float* __restrict__ fr1_b,
    const float* __restrict__ fr1pv_w, const float* __restrict__ fr1pv_b,
    const float* __restrict__ fr2_w, const float* __restrict__ fr3_w,
    const float* __restrict__ fr2pv_w, const float* __restrict__ fr3pv_w,
    const float* __restrict__ fo1_w, const float* __restrict__ fo2_w,
    const float* __restrict__ fo3_w,
    float* __restrict__ A1f, float* __restrict__ B1,
    float* __restrict__ A1pvf, float* __restrict__ B1pv,
    _Float16* __restrict__ WT, float* __restrict__ dout) {
  int blk = blockIdx.x;
  int tid = threadIdx.x;
  if (blk < 384) {
    int mat = blk >> 7, b = blk & 127;
    __shared__ float sxT[NN * 33];
    for (int i = tid; i < NN * PP; i += 256) {
      int p = i >> 6, n = i & 63;
      sxT[n * 33 + p] = x[b * (PP * NN) + i];
    }
    __syncthreads();
    const float* w; float* outp; const float* bias;
    if (mat == 0)      { w = fr1_w;           outp = A1f;   bias = fr1_b; }
    else if (mat == 1) { w = fr1_w + 32 * HH; outp = B1;    bias = nullptr; }
    else               { w = fr1pv_w;         outp = A1pvf; bias = fr1pv_b; }
    for (int o = tid; o < NN * 32; o += 256) {
      int n = o >> 5, jc = o & 31;
      float4 acc = {0.f, 0.f, 0.f, 0.f};
      const float* xr = &sxT[n * 33];
#pragma unroll 8
      for (int k = 0; k < PP; k++) {
        float xv = xr[k];
        float4 wv = ((const float4*)w)[k * 32 + jc];
        acc.x += xv * wv.x; acc.y += xv * wv.y;
        acc.z += xv * wv.z; acc.w += xv * wv.w;
      }
      if (bias) {
        float4 bv = ((const float4*)bias)[jc];
        acc.x += bv.x; acc.y += bv.y; acc.z += bv.z; acc.w += bv.w;
      }
      ((float4*)outp)[(b * NN + n) * 32 + jc] = acc;
    }
  } else if (blk < 512) {
    int b = blk - 384;
    __shared__ float syT[NV * 15];
    for (int i = tid; i < SS * NV; i += 256) {
      int s = i / NV, v = i - s * NV;
      syT[v * 15 + s] = y[b * (SS * NV) + i];
    }
    __syncthreads();
    const float4* w4 = (const float4*)(fr1pv_w + 32 * HH);
    for (int o = tid; o < NV * 32; o += 256) {
      int v = o >> 5, jc = o & 31;
      float4 acc = {0.f, 0.f, 0.f, 0.f};
#pragma unroll
      for (int s = 0; s < SS; s++) {
        float yv = syT[v * 15 + s];
        float4 wv = w4[s * 32 + jc];
        acc.x += yv * wv.x; acc.y += yv * wv.y;
        acc.z += yv * wv.z; acc.w += yv * wv.w;
      }
      ((float4*)B1pv)[(b * NV + v) * 32 + jc] = acc;
    }
  } else if (blk < 519) {
    // frag-major: dst[((nt*NKS+ks)*64 + lane)*8 + j] = src[(ks*32+q*8+j)*N + nt*16+c]
    int wid = blk - 512;
    const float* src; int N, NKS, NTN; _Float16* dst;
    switch (wid) {
      case 0: src = fr2_w;   N = 128; NKS = 4; NTN = 8; dst = WT + OFF_W2;   break;
      case 1: src = fr3_w;   N = 64;  NKS = 4; NTN = 4; dst = WT + OFF_W3;   break;
      case 2: src = fr2pv_w; N = 128; NKS = 4; NTN = 8; dst = WT + OFF_W2PV; break;
      case 3: src = fr3pv_w; N = 64;  NKS = 4; NTN = 4; dst = WT + OFF_W3PV; break;
      case 4: src = fo1_w;   N = 128; NKS = 5; NTN = 8; dst = WT + OFF_FO1;  break;
      case 5: src = fo2_w;   N = 128; NKS = 4; NTN = 8; dst = WT + OFF_FO2;  break;
      default: src = fo3_w;  N = 64;  NKS = 4; NTN = 4; dst = WT + OFF_FO3;  break;
    }
    int tot = NTN * NKS * 512;
    for (int i = tid; i < tot; i += 256) {
      int j = i & 7, l = (i >> 3) & 63, f = i >> 9;
      int ks = f % NKS, nt = f / NKS;
      int cc = l & 15, qq = l >> 4;
      dst[i] = (_Float16)src[(ks * 32 + qq * 8 + j) * N + nt * 16 + cc];
    }
  } else {
    for (int i = tid; i < NB * NCLS; i += 256) dout[i] = 0.f;
  }
}

// layers 2+3 on one 128-row chunk (wave owns rows wrow..wrow+31, no barrier needed)
template <int DIVR, int NROWS>
__device__ __forceinline__ void layers23(
    const half8 (&hf)[2][4],
    const _Float16* __restrict__ W2fm, const _Float16* __restrict__ W3fm,
    const float* __restrict__ b2, const float* __restrict__ b3,
    _Float16* __restrict__ sH, float* __restrict__ sEb,
    int wrow, int chbase, int lane) {
  int c = lane & 15, q = lane >> 4;
  // layer2 transposed-C: D^T = W2^T(A) x h1^T(B)
#pragma unroll
  for (int nt = 0; nt < 8; nt++) {
    floatx4 a0 = {0.f, 0.f, 0.f, 0.f}, a1 = {0.f, 0.f, 0.f, 0.f};
#pragma unroll
    for (int ks = 0; ks < 4; ks++) {
      half8 wf = *(const half8*)(&W2fm[((nt * 4 + ks) << 9) + (lane << 3)]);
      a0 = MFMA(wf, hf[0][ks], a0);
      a1 = MFMA(wf, hf[1][ks], a1);
    }
    float4 bb = *(const float4*)(&b2[nt * 16 + q * 4]);
    half4v h0, h1v;
    h0[0] = (_Float16)fmaxf(a0[0] + bb.x, 0.f);
    h0[1] = (_Float16)fmaxf(a0[1] + bb.y, 0.f);
    h0[2] = (_Float16)fmaxf(a0[2] + bb.z, 0.f);
    h0[3] = (_Float16)fmaxf(a0[3] + bb.w, 0.f);
    h1v[0] = (_Float16)fmaxf(a1[0] + bb.x, 0.f);
    h1v[1] = (_Float16)fmaxf(a1[1] + bb.y, 0.f);
    h1v[2] = (_Float16)fmaxf(a1[2] + bb.z, 0.f);
    h1v[3] = (_Float16)fmaxf(a1[3] + bb.w, 0.f);
    *(half4v*)(&sH[(wrow + c) * PITCH + nt * 16 + q * 4]) = h0;
    *(half4v*)(&sH[(wrow + 16 + c) * PITCH + nt * 16 + q * 4]) = h1v;
  }
  // layer3: E = h2(A) @ W3(B)
  half8 a2[2][4];
#pragma unroll
  for (int mt = 0; mt < 2; mt++)
#pragma unroll
    for (int ks = 0; ks < 4; ks++)
      a2[mt][ks] = *(const half8*)(&sH[(wrow + mt * 16 + c) * PITCH + ks * 32 + q * 8]);
#pragma unroll
  for (int nt = 0; nt < 4; nt++) {
    floatx4 e0 = {0.f, 0.f, 0.f, 0.f}, e1 = {0.f, 0.f, 0.f, 0.f};
#pragma unroll
    for (int ks = 0; ks < 4; ks++) {
      half8 wf = *(const half8*)(&W3fm[((nt * 4 + ks) << 9) + (lane << 3)]);
      e0 = MFMA(a2[0][ks], wf, e0);
      e1 = MFMA(a2[1][ks], wf, e1);
    }
    int col = nt * 16 + c;
    float bb = b3[col];
#pragma unroll
    for (int mt = 0; mt < 2; mt++) {
      floatx4 ac = mt ? e1 : e0;
      int rbase = chbase + wrow + mt * 16 + q * 4;
      if (rbase < NROWS) {
        float v0 = fmaxf(ac[0] + bb, 0.f);
        float v1 = fmaxf(ac[1] + bb, 0.f);
        float v2 = fmaxf(ac[2] + bb, 0.f);
        float v3 = fmaxf(ac[3] + bb, 0.f);
        int rrA = rbase / DIVR, rrB = (rbase + 3) / DIVR;
        if (rrA == rrB && rbase + 3 < NROWS) {
          atomicAdd(&sEb[rrA * 64 + col], v0 + v1 + v2 + v3);
        } else {
          float vs[4] = {v0, v1, v2, v3};
          for (int rg = 0; rg < 4; rg++) {
            int r2 = rbase + rg;
            if (r2 < NROWS) atomicAdd(&sEb[(r2 / DIVR) * 64 + col], vs[rg]);
          }
        }
      }
    }
  }
}

// ---------------- MEGA: pp edges + pv edges + node MLP + pool + fc, per (b, 8 nodes) ----------------
__global__ __launch_bounds__(256, 4) void mega(
    const float* __restrict__ A1f, const float* __restrict__ B1,
    const float* __restrict__ A1pvf, const float* __restrict__ B1pv,
    const float* __restrict__ x,
    const float* __restrict__ fr2_b, const float* __restrict__ fr3_b,
    const float* __restrict__ fr2pv_b, const float* __restrict__ fr3pv_b,
    const float* __restrict__ fo1_b, const float* __restrict__ fo2_b,
    const float* __restrict__ fo3_b,
    const float* __restrict__ fc_w, const float* __restrict__ fc_b,
    const _Float16* __restrict__ WT, float* __restrict__ out) {
  __shared__ _Float16 sH[128 * PITCH];   // 34816 B, multi-purpose
  __shared__ float sEpp[8 * 64];
  __shared__ float sEpv[8 * 64];
  __shared__ float sPool[64];
  int tid = threadIdx.x;
  int b = blockIdx.x >> 3, r0 = (blockIdx.x & 7) << 3;
  for (int i = tid; i < 512; i += 256) { sEpp[i] = 0.f; sEpv[i] = 0.f; }
  __syncthreads();
  int lane = tid & 63, wv = tid >> 6;
  int c = lane & 15, q = lane >> 4;
  int wrow = wv * 32;
  const float* A1b = A1f + (b * NN + r0) * HH;
  const float* B1b = B1 + b * NN * HH;
  // ---- 4 pp chunks (504 rows: 8 receivers x 63 senders) ----
  for (int ch = 0; ch < 4; ch++) {
    half8 hf[2][4];
#pragma unroll
    for (int mt = 0; mt < 2; mt++) {
      int rl = ch * 128 + wrow + mt * 16 + c;
      bool valid = rl < 504;
      int rr = rl / 63; if (rr > 7) rr = 7;
      int jj = rl - rr * 63; if (jj > 62) jj = 62;
      int r = r0 + rr;
      int s = jj + (jj >= r ? 1 : 0);
      const float* ap = A1b + rr * HH + q * 8;
      const float* bp = B1b + s * HH + q * 8;
#pragma unroll
      for (int ks = 0; ks < 4; ks++) {
        half8 h = {};
        if (valid) {
          float4 x0 = *(const float4*)(bp + ks * 32);
          float4 x1 = *(const float4*)(bp + ks * 32 + 4);
          float4 y0 = *(const float4*)(ap + ks * 32);
          float4 y1 = *(const float4*)(ap + ks * 32 + 4);
          h[0] = (_Float16)fmaxf(x0.x + y0.x, 0.f);
          h[1] = (_Float16)fmaxf(x0.y + y0.y, 0.f);
          h[2] = (_Float16)fmaxf(x0.z + y0.z, 0.f);
          h[3] = (_Float16)fmaxf(x0.w + y0.w, 0.f);
          h[4] = (_Float16)fmaxf(x1.x + y1.x, 0.f);
          h[5] = (_Float16)fmaxf(x1.y + y1.y, 0.f);
          h[6] = (_Float16)fmaxf(x1.z + y1.z, 0.f);
          h[7] = (_Float16)fmaxf(x1.w + y1.w, 0.f);
        }
        hf[mt][ks] = h;
      }
    }
    layers23<63, 504>(hf, WT + OFF_W2, WT + OFF_W3, fr2_b, fr3_b,
                      sH, sEpp, wrow, ch * 128, lane);
  }
  // ---- 1 pv chunk (112 rows: 8 k-nodes x 14 vertices) ----
  {
    half8 hf[2][4];
#pragma unroll
    for (int mt = 0; mt < 2; mt++) {
      int rl = wrow + mt * 16 + c;
      bool valid = rl < 112;
      int rr = rl / 14; if (rr > 7) rr = 7;
      int v = rl - rr * 14; if (v > 13) v = 13;
      const float* ap = A1pvf + (b * NN + r0 + rr) * HH + q * 8;
      const float* bp = B1pv + (b * NV + v) * HH + q * 8;
#pragma unroll
      for (int ks = 0; ks < 4; ks++) {
        half8 h = {};
        if (valid) {
          float4 x0 = *(const float4*)(bp + ks * 32);
          float4 x1 = *(const float4*)(bp + ks * 32 + 4);
          float4 y0 = *(const float4*)(ap + ks * 32);
          float4 y1 = *(const float4*)(ap + ks * 32 + 4);
          h[0] = (_Float16)fmaxf(x0.x + y0.x, 0.f);
          h[1] = (_Float16)fmaxf(x0.y + y0.y, 0.f);
          h[2] = (_Float16)fmaxf(x0.z + y0.z, 0.f);
          h[3] = (_Float16)fmaxf(x0.w + y0.w, 0.f);
          h[4] = (_Float16)fmaxf(x1.x + y1.x, 0.f);
          h[5] = (_Float16)fmaxf(x1.y + y1.y, 0.f);
          h[6] = (_Float16)fmaxf(x1.z + y1.z, 0.f);
          h[7] = (_Float16)fmaxf(x1.w + y1.w, 0.f);
        }
        hf[mt][ks] = h;
      }
    }
    layers23<14, 112>(hf, WT + OFF_W2PV, WT + OFF_W3PV, fr2pv_b, fr3pv_b,
                      sH, sEpv, wrow, 0, lane);
  }
  __syncthreads();
  // ---- node stage: C = [x | Ebar_pp | Ebar_pv] for this block's 8 nodes ----
  _Float16* sC  = &sH[64 * PITCH];   // 16 x 168 (overlay, rows 64.. of sH)
  _Float16* sHa = &sH[0];            // 16 x PITCH
  _Float16* sHb = &sH[32 * PITCH];   // 16 x PITCH
  for (int i = tid; i < 16 * 32; i += 256) {
    int row = i >> 5, p = i & 31;
    float v = (row < 8) ? x[b * (PP * NN) + p * 64 + r0 + row] : 0.f;
    sC[row * 168 + p] = (_Float16)v;
  }
  for (int i = tid; i < 16 * 64; i += 256) {
    int row = i >> 6, d = i & 63;
    float vpp = (row < 8) ? sEpp[row * 64 + d] : 0.f;
    float vpv = (row < 8) ? sEpv[row * 64 + d] : 0.f;
    sC[row * 168 + 32 + d] = (_Float16)vpp;
    sC[row * 168 + 96 + d] = (_Float16)vpv;
  }
  __syncthreads();
  // fo1 (K=160), transposed-C; wave owns cols wv*32..+31
  half8 cf[5];
#pragma unroll
  for (int ks = 0; ks < 5; ks++)
    cf[ks] = *(const half8*)(&sC[c * 168 + ks * 32 + q * 8]);
#pragma unroll
  for (int nt2 = 0; nt2 < 2; nt2++) {
    int nt = wv * 2 + nt2;
    floatx4 a0 = {0.f, 0.f, 0.f, 0.f};
#pragma unroll
    for (int ks = 0; ks < 5; ks++) {
      half8 wf = *(const half8*)(&WT[OFF_FO1 + ((nt * 5 + ks) << 9) + (lane << 3)]);
      a0 = MFMA(wf, cf[ks], a0);
    }
    float4 bb = *(const float4*)(&fo1_b[nt * 16 + q * 4]);
    half4v h0;
    h0[0] = (_Float16)fmaxf(a0[0] + bb.x, 0.f);
    h0[1] = (_Float16)fmaxf(a0[1] + bb.y, 0.f);
    h0[2] = (_Float16)fmaxf(a0[2] + bb.z, 0.f);
    h0[3] = (_Float16)fmaxf(a0[3] + bb.w, 0.f);
    *(half4v*)(&sHa[c * PITCH + nt * 16 + q * 4]) = h0;
  }
  __syncthreads();
  // fo2 (K=128), transposed-C
  half8 g1[4];
#pragma unroll
  for (int ks = 0; ks < 4; ks++)
    g1[ks] = *(const half8*)(&sHa[c * PITCH + ks * 32 + q * 8]);
#pragma unroll
  for (int nt2 = 0; nt2 < 2; nt2++) {
    int nt = wv * 2 + nt2;
    floatx4 a0 = {0.f, 0.f, 0.f, 0.f};
#pragma unroll
    for (int ks = 0; ks < 4; ks++) {
      half8 wf = *(const half8*)(&WT[OFF_FO2 + ((nt * 4 + ks) << 9) + (lane << 3)]);
      a0 = MFMA(wf, g1[ks], a0);
    }
    float4 bb = *(const float4*)(&fo2_b[nt * 16 + q * 4]);
    half4v h0;
    h0[0] = (_Float16)fmaxf(a0[0] + bb.x, 0.f);
    h0[1] = (_Float16)fmaxf(a0[1] + bb.y, 0.f);
    h0[2] = (_Float16)fmaxf(a0[2] + bb.z, 0.f);
    h0[3] = (_Float16)fmaxf(a0[3] + bb.w, 0.f);
    *(half4v*)(&sHb[c * PITCH + nt * 16 + q * 4]) = h0;
  }
  __syncthreads();
  // fo3 (N=64): wave owns 16 cols; pool over the 8 real nodes
  half8 g2[4];
#pragma unroll
  for (int ks = 0; ks < 4; ks++)
    g2[ks] = *(const half8*)(&sHb[c * PITCH + ks * 32 + q * 8]);
  floatx4 e0 = {0.f, 0.f, 0.f, 0.f};
#pragma unroll
  for (int ks = 0; ks < 4; ks++) {
    half8 wf = *(const half8*)(&WT[OFF_FO3 + ((wv * 4 + ks) << 9) + (lane << 3)]);
    e0 = MFMA(g2[ks], wf, e0);
  }
  float bb3 = fo3_b[wv * 16 + c];
  float s = 0.f;
  if (q < 2) {
#pragma unroll
    for (int rg = 0; rg < 4; rg++) s += fmaxf(e0[rg] + bb3, 0.f);
  }
  s += __shfl_xor(s, 16);
  if (lane < 16) sPool[wv * 16 + c] = s;
  __syncthreads();
  if (tid < NCLS) {
    float o = (r0 == 0) ? fc_b[tid] : 0.f;
#pragma unroll
    for (int d = 0; d < 64; d++) o += sPool[d] * fc_w[d * NCLS + tid];
    atomicAdd(&out[b * NCLS + tid], o);
  }
}

extern "C" void kernel_launch(void* const* d_in, const int* in_sizes, int n_in,
                              void* d_out, int out_size, void* d_ws, size_t ws_size,
                              hipStream_t stream) {
  const float* x = (const float*)d_in[0];
  const float* y = (const float*)d_in[1];
  const float* fr1_w = (const float*)d_in[2];  const float* fr1_b = (const float*)d_in[3];
  const float* fr2_w = (const float*)d_in[4];  const float* fr2_b = (const float*)d_in[5];
  const float* fr3_w = (const float*)d_in[6];  const float* fr3_b = (const float*)d_in[7];
  const float* fr1pv_w = (const float*)d_in[8];  const float* fr1pv_b = (const float*)d_in[9];
  const float* fr2pv_w = (const float*)d_in[10]; const float* fr2pv_b = (const float*)d_in[11];
  const float* fr3pv_w = (const float*)d_in[12]; const float* fr3pv_b = (const float*)d_in[13];
  const float* fo1_w = (const float*)d_in[14];  const float* fo1_b = (const float*)d_in[15];
  const float* fo2_w = (const float*)d_in[16];  const float* fo2_b = (const float*)d_in[17];
  const float* fo3_w = (const float*)d_in[18];  const float* fo3_b = (const float*)d_in[19];
  const float* fc_w = (const float*)d_in[20];   const float* fc_b = (const float*)d_in[21];

  char* ws = (char*)d_ws;
  float* A1f   = (float*)(ws);                   // [128][64][128] f32, 4 MB (bias folded)
  float* B1    = (float*)(ws + (4u << 20));      // 4 MB
  float* A1pvf = (float*)(ws + (8u << 20));      // 4 MB (bias folded)
  float* B1pv  = (float*)(ws + (12u << 20));     // [128][14][128] f32
  _Float16* WT = (_Float16*)(ws + (13u << 20));  // frag-major fp16 weights (~184 KB)

  k0_prep<<<520, 256, 0, stream>>>(x, y, fr1_w, fr1_b, fr1pv_w, fr1pv_b,
                                   fr2_w, fr3_w, fr2pv_w, fr3pv_w,
                                   fo1_w, fo2_w, fo3_w,
                                   A1f, B1, A1pvf, B1pv, WT, (float*)d_out);
  mega<<<NB * 8, 256, 0, stream>>>(A1f, B1, A1pvf, B1pv, x,
                                   fr2_b, fr3_b, fr2pv_b, fr3pv_b,
                                   fo1_b, fo2_b, fo3_b, fc_w, fc_b,
                                   WT, (float*)d_out);
}

// Round 4
// 237.066 us; speedup vs baseline: 1.4808x; 1.4808x over previous
//
#include <hip/hip_runtime.h>

typedef __attribute__((ext_vector_type(8))) _Float16 half8;
typedef __attribute__((ext_vector_type(4))) _Float16 half4v;
typedef __attribute__((ext_vector_type(4))) float floatx4;

#define NB 128
#define NN 64
#define NV 14
#define PP 32
#define SS 14
#define HH 128
#define DE 64
#define NCLS 5
#define PITCH 136   // halves; 272 B rows -> 2-way-max bank aliasing (free)

// fragment-major weight offsets (halves). layout: [nt][ks][lane][8]
#define OFF_W2   0
#define OFF_W3   16384
#define OFF_W2PV 24576
#define OFF_W3PV 40960
#define OFF_FO1  49152
#define OFF_FO2  69632
#define OFF_FO3  86016

__device__ __forceinline__ floatx4 MFMA(half8 a, half8 b, floatx4 c) {
  return __builtin_amdgcn_mfma_f32_16x16x32_f16(a, b, c, 0, 0, 0);
}

// ---------------- K0: fp16 layer-1 terms (+bias fold), frag-major weights, d_out zero ----------------
__global__ __launch_bounds__(256) void k0_prep(
    const float* __restrict__ x, const float* __restrict__ y,
    const float* __restrict__ fr1_w, const float* __restrict__ fr1_b,
    const float* __restrict__ fr1pv_w, const float* __restrict__ fr1pv_b,
    const float* __restrict__ fr2_w, const float* __restrict__ fr3_w,
    const float* __restrict__ fr2pv_w, const float* __restrict__ fr3pv_w,
    const float* __restrict__ fo1_w, const float* __restrict__ fo2_w,
    const float* __restrict__ fo3_w,
    _Float16* __restrict__ A1h, _Float16* __restrict__ B1h,
    _Float16* __restrict__ A1pvh, _Float16* __restrict__ B1pvh,
    _Float16* __restrict__ WT, float* __restrict__ dout) {
  int blk = blockIdx.x;
  int tid = threadIdx.x;
  if (blk < 384) {
    int mat = blk >> 7, b = blk & 127;
    __shared__ float sxT[NN * 33];
    for (int i = tid; i < NN * PP; i += 256) {
      int p = i >> 6, n = i & 63;
      sxT[n * 33 + p] = x[b * (PP * NN) + i];
    }
    __syncthreads();
    const float* w; _Float16* outp; const float* bias;
    if (mat == 0)      { w = fr1_w;           outp = A1h;   bias = fr1_b; }
    else if (mat == 1) { w = fr1_w + 32 * HH; outp = B1h;   bias = nullptr; }
    else               { w = fr1pv_w;         outp = A1pvh; bias = fr1pv_b; }
    for (int o = tid; o < NN * 32; o += 256) {
      int n = o >> 5, jc = o & 31;
      float4 acc = {0.f, 0.f, 0.f, 0.f};
      const float* xr = &sxT[n * 33];
#pragma unroll 8
      for (int k = 0; k < PP; k++) {
        float xv = xr[k];
        float4 wv = ((const float4*)w)[k * 32 + jc];
        acc.x += xv * wv.x; acc.y += xv * wv.y;
        acc.z += xv * wv.z; acc.w += xv * wv.w;
      }
      if (bias) {
        float4 bv = ((const float4*)bias)[jc];
        acc.x += bv.x; acc.y += bv.y; acc.z += bv.z; acc.w += bv.w;
      }
      half4v hv;
      hv[0] = (_Float16)acc.x; hv[1] = (_Float16)acc.y;
      hv[2] = (_Float16)acc.z; hv[3] = (_Float16)acc.w;
      *(half4v*)(&outp[(b * NN + n) * HH + jc * 4]) = hv;
    }
  } else if (blk < 512) {
    int b = blk - 384;
    __shared__ float syT[NV * 15];
    for (int i = tid; i < SS * NV; i += 256) {
      int s = i / NV, v = i - s * NV;
      syT[v * 15 + s] = y[b * (SS * NV) + i];
    }
    __syncthreads();
    const float4* w4 = (const float4*)(fr1pv_w + 32 * HH);
    for (int o = tid; o < NV * 32; o += 256) {
      int v = o >> 5, jc = o & 31;
      float4 acc = {0.f, 0.f, 0.f, 0.f};
#pragma unroll
      for (int s = 0; s < SS; s++) {
        float yv = syT[v * 15 + s];
        float4 wv = w4[s * 32 + jc];
        acc.x += yv * wv.x; acc.y += yv * wv.y;
        acc.z += yv * wv.z; acc.w += yv * wv.w;
      }
      half4v hv;
      hv[0] = (_Float16)acc.x; hv[1] = (_Float16)acc.y;
      hv[2] = (_Float16)acc.z; hv[3] = (_Float16)acc.w;
      *(half4v*)(&B1pvh[(b * NV + v) * HH + jc * 4]) = hv;
    }
  } else if (blk < 519) {
    // frag-major: dst[((nt*NKS+ks)*64 + lane)*8 + j] = src[(ks*32+q*8+j)*N + nt*16+c]
    int wid = blk - 512;
    const float* src; int N, NKS, NTN; _Float16* dst;
    switch (wid) {
      case 0: src = fr2_w;   N = 128; NKS = 4; NTN = 8; dst = WT + OFF_W2;   break;
      case 1: src = fr3_w;   N = 64;  NKS = 4; NTN = 4; dst = WT + OFF_W3;   break;
      case 2: src = fr2pv_w; N = 128; NKS = 4; NTN = 8; dst = WT + OFF_W2PV; break;
      case 3: src = fr3pv_w; N = 64;  NKS = 4; NTN = 4; dst = WT + OFF_W3PV; break;
      case 4: src = fo1_w;   N = 128; NKS = 5; NTN = 8; dst = WT + OFF_FO1;  break;
      case 5: src = fo2_w;   N = 128; NKS = 4; NTN = 8; dst = WT + OFF_FO2;  break;
      default: src = fo3_w;  N = 64;  NKS = 4; NTN = 4; dst = WT + OFF_FO3;  break;
    }
    int tot = NTN * NKS * 512;
    for (int i = tid; i < tot; i += 256) {
      int j = i & 7, l = (i >> 3) & 63, f = i >> 9;
      int ks = f % NKS, nt = f / NKS;
      int cc = l & 15, qq = l >> 4;
      dst[i] = (_Float16)src[(ks * 32 + qq * 8 + j) * N + nt * 16 + cc];
    }
  } else {
    for (int i = tid; i < NB * NCLS; i += 256) dout[i] = 0.f;
  }
}

// layers 2+3 on one 128-row chunk (wave owns rows wrow..wrow+31, no barrier needed)
template <int DIVR, int NROWS>
__device__ __forceinline__ void layers23(
    const half8 (&hf)[2][4],
    const _Float16* __restrict__ W2fm, const _Float16* __restrict__ W3fm,
    const float* __restrict__ b2, const float* __restrict__ b3,
    _Float16* __restrict__ sH, float* __restrict__ sEb,
    int wrow, int chbase, int lane) {
  int c = lane & 15, q = lane >> 4;
  // layer2 transposed-C: D^T = W2^T(A) x h1^T(B)
#pragma unroll
  for (int nt = 0; nt < 8; nt++) {
    floatx4 a0 = {0.f, 0.f, 0.f, 0.f}, a1 = {0.f, 0.f, 0.f, 0.f};
#pragma unroll
    for (int ks = 0; ks < 4; ks++) {
      half8 wf = *(const half8*)(&W2fm[((nt * 4 + ks) << 9) + (lane << 3)]);
      a0 = MFMA(wf, hf[0][ks], a0);
      a1 = MFMA(wf, hf[1][ks], a1);
    }
    float4 bb = *(const float4*)(&b2[nt * 16 + q * 4]);
    half4v h0, h1v;
    h0[0] = (_Float16)fmaxf(a0[0] + bb.x, 0.f);
    h0[1] = (_Float16)fmaxf(a0[1] + bb.y, 0.f);
    h0[2] = (_Float16)fmaxf(a0[2] + bb.z, 0.f);
    h0[3] = (_Float16)fmaxf(a0[3] + bb.w, 0.f);
    h1v[0] = (_Float16)fmaxf(a1[0] + bb.x, 0.f);
    h1v[1] = (_Float16)fmaxf(a1[1] + bb.y, 0.f);
    h1v[2] = (_Float16)fmaxf(a1[2] + bb.z, 0.f);
    h1v[3] = (_Float16)fmaxf(a1[3] + bb.w, 0.f);
    *(half4v*)(&sH[(wrow + c) * PITCH + nt * 16 + q * 4]) = h0;
    *(half4v*)(&sH[(wrow + 16 + c) * PITCH + nt * 16 + q * 4]) = h1v;
  }
  // layer3: E = h2(A) @ W3(B)
  half8 a2[2][4];
#pragma unroll
  for (int mt = 0; mt < 2; mt++)
#pragma unroll
    for (int ks = 0; ks < 4; ks++)
      a2[mt][ks] = *(const half8*)(&sH[(wrow + mt * 16 + c) * PITCH + ks * 32 + q * 8]);
#pragma unroll
  for (int nt = 0; nt < 4; nt++) {
    floatx4 e0 = {0.f, 0.f, 0.f, 0.f}, e1 = {0.f, 0.f, 0.f, 0.f};
#pragma unroll
    for (int ks = 0; ks < 4; ks++) {
      half8 wf = *(const half8*)(&W3fm[((nt * 4 + ks) << 9) + (lane << 3)]);
      e0 = MFMA(a2[0][ks], wf, e0);
      e1 = MFMA(a2[1][ks], wf, e1);
    }
    int col = nt * 16 + c;
    float bb = b3[col];
#pragma unroll
    for (int mt = 0; mt < 2; mt++) {
      floatx4 ac = mt ? e1 : e0;
      int rbase = chbase + wrow + mt * 16 + q * 4;
      if (rbase < NROWS) {
        float v0 = fmaxf(ac[0] + bb, 0.f);
        float v1 = fmaxf(ac[1] + bb, 0.f);
        float v2 = fmaxf(ac[2] + bb, 0.f);
        float v3 = fmaxf(ac[3] + bb, 0.f);
        int rrA = rbase / DIVR, rrB = (rbase + 3) / DIVR;
        if (rrA == rrB && rbase + 3 < NROWS) {
          atomicAdd(&sEb[rrA * 64 + col], v0 + v1 + v2 + v3);
        } else {
          float vs[4] = {v0, v1, v2, v3};
#pragma unroll
          for (int rg = 0; rg < 4; rg++) {
            int r2 = rbase + rg;
            if (r2 < NROWS) atomicAdd(&sEb[(r2 / DIVR) * 64 + col], vs[rg]);
          }
        }
      }
    }
  }
}

// ---------------- MEGA: pp + pv edges + node MLP + pool + fc, per (b, 8 nodes) ----------------
__global__ __launch_bounds__(256) void mega(
    const _Float16* __restrict__ A1h, const _Float16* __restrict__ B1h,
    const _Float16* __restrict__ A1pvh, const _Float16* __restrict__ B1pvh,
    const float* __restrict__ x,
    const float* __restrict__ fr2_b, const float* __restrict__ fr3_b,
    const float* __restrict__ fr2pv_b, const float* __restrict__ fr3pv_b,
    const float* __restrict__ fo1_b, const float* __restrict__ fo2_b,
    const float* __restrict__ fo3_b,
    const float* __restrict__ fc_w, const float* __restrict__ fc_b,
    const _Float16* __restrict__ WT, float* __restrict__ out) {
  __shared__ _Float16 sH[128 * PITCH];    // 34816 B (wave-partitioned h2; sC overlays rows 64+)
  __shared__ _Float16 sB1[64 * PITCH];    // 17408 B  this batch's B1h
  __shared__ _Float16 sA1[8 * PITCH];     // 2176 B   block's receivers A1h (+b1)
  __shared__ _Float16 sApv[8 * PITCH];    // 2176 B
  __shared__ _Float16 sBpv[14 * PITCH];   // 3808 B
  __shared__ float sEpp[8 * 64];
  __shared__ float sEpv[8 * 64];
  __shared__ float sPool[64];
  int tid = threadIdx.x;
  int b = blockIdx.x >> 3, r0 = (blockIdx.x & 7) << 3;
  for (int i = tid; i < 512; i += 256) { sEpp[i] = 0.f; sEpv[i] = 0.f; }
  // stage fp16 operand tiles (coalesced uint4 = 8 halves)
  for (int i = tid; i < 64 * 16; i += 256) {
    int row = i >> 4, cc = i & 15;
    *(uint4*)(&sB1[row * PITCH + cc * 8]) = *(const uint4*)(&B1h[(b * NN + row) * HH + cc * 8]);
  }
  for (int i = tid; i < 8 * 16; i += 256) {
    int row = i >> 4, cc = i & 15;
    *(uint4*)(&sA1[row * PITCH + cc * 8]) = *(const uint4*)(&A1h[(b * NN + r0 + row) * HH + cc * 8]);
    *(uint4*)(&sApv[row * PITCH + cc * 8]) = *(const uint4*)(&A1pvh[(b * NN + r0 + row) * HH + cc * 8]);
  }
  for (int i = tid; i < 14 * 16; i += 256) {
    int row = i >> 4, cc = i & 15;
    *(uint4*)(&sBpv[row * PITCH + cc * 8]) = *(const uint4*)(&B1pvh[(b * NV + row) * HH + cc * 8]);
  }
  __syncthreads();
  int lane = tid & 63, wv = tid >> 6;
  int c = lane & 15, q = lane >> 4;
  int wrow = wv * 32;
  // ---- 4 pp chunks (504 rows: 8 receivers x 63 senders; rows >= 504 computed & discarded) ----
  for (int ch = 0; ch < 4; ch++) {
    half8 hf[2][4];
#pragma unroll
    for (int mt = 0; mt < 2; mt++) {
      int rl = ch * 128 + wrow + mt * 16 + c;
      int rr = rl / 63; if (rr > 7) rr = 7;
      int jj = rl - rr * 63; if (jj > 62) jj = 62;
      int r = r0 + rr;
      int s = jj + (jj >= r ? 1 : 0);
#pragma unroll
      for (int ks = 0; ks < 4; ks++) {
        half8 av = *(const half8*)(&sA1[rr * PITCH + ks * 32 + q * 8]);
        half8 bv = *(const half8*)(&sB1[s * PITCH + ks * 32 + q * 8]);
        half8 h = av + bv;
#pragma unroll
        for (int j = 0; j < 8; j++) h[j] = h[j] > (_Float16)0.f ? h[j] : (_Float16)0.f;
        hf[mt][ks] = h;
      }
    }
    layers23<63, 504>(hf, WT + OFF_W2, WT + OFF_W3, fr2_b, fr3_b,
                      sH, sEpp, wrow, ch * 128, lane);
  }
  // ---- 1 pv chunk (112 rows: 8 k-nodes x 14 vertices) ----
  {
    half8 hf[2][4];
#pragma unroll
    for (int mt = 0; mt < 2; mt++) {
      int rl = wrow + mt * 16 + c;
      int rr = rl / 14; if (rr > 7) rr = 7;
      int v = rl - rr * 14; if (v > 13) v = 13;
#pragma unroll
      for (int ks = 0; ks < 4; ks++) {
        half8 av = *(const half8*)(&sApv[rr * PITCH + ks * 32 + q * 8]);
        half8 bv = *(const half8*)(&sBpv[v * PITCH + ks * 32 + q * 8]);
        half8 h = av + bv;
#pragma unroll
        for (int j = 0; j < 8; j++) h[j] = h[j] > (_Float16)0.f ? h[j] : (_Float16)0.f;
        hf[mt][ks] = h;
      }
    }
    layers23<14, 112>(hf, WT + OFF_W2PV, WT + OFF_W3PV, fr2pv_b, fr3pv_b,
                      sH, sEpv, wrow, 0, lane);
  }
  __syncthreads();
  // ---- node stage: C = [x | Ebar_pp | Ebar_pv] for this block's 8 nodes ----
  _Float16* sC  = &sH[64 * PITCH];   // 16 x 168 overlay
  _Float16* sHa = &sH[0];            // 16 x PITCH
  _Float16* sHb = &sH[32 * PITCH];   // 16 x PITCH
  for (int i = tid; i < 16 * 32; i += 256) {
    int row = i >> 5, p = i & 31;
    float v = (row < 8) ? x[b * (PP * NN) + p * 64 + r0 + row] : 0.f;
    sC[row * 168 + p] = (_Float16)v;
  }
  for (int i = tid; i < 16 * 64; i += 256) {
    int row = i >> 6, d = i & 63;
    float vpp = (row < 8) ? sEpp[row * 64 + d] : 0.f;
    float vpv = (row < 8) ? sEpv[row * 64 + d] : 0.f;
    sC[row * 168 + 32 + d] = (_Float16)vpp;
    sC[row * 168 + 96 + d] = (_Float16)vpv;
  }
  __syncthreads();
  // fo1 (K=160), transposed-C; wave owns cols wv*32..+31
  half8 cf[5];
#pragma unroll
  for (int ks = 0; ks < 5; ks++)
    cf[ks] = *(const half8*)(&sC[c * 168 + ks * 32 + q * 8]);
#pragma unroll
  for (int nt2 = 0; nt2 < 2; nt2++) {
    int nt = wv * 2 + nt2;
    floatx4 a0 = {0.f, 0.f, 0.f, 0.f};
#pragma unroll
    for (int ks = 0; ks < 5; ks++) {
      half8 wf = *(const half8*)(&WT[OFF_FO1 + ((nt * 5 + ks) << 9) + (lane << 3)]);
      a0 = MFMA(wf, cf[ks], a0);
    }
    float4 bb = *(const float4*)(&fo1_b[nt * 16 + q * 4]);
    half4v h0;
    h0[0] = (_Float16)fmaxf(a0[0] + bb.x, 0.f);
    h0[1] = (_Float16)fmaxf(a0[1] + bb.y, 0.f);
    h0[2] = (_Float16)fmaxf(a0[2] + bb.z, 0.f);
    h0[3] = (_Float16)fmaxf(a0[3] + bb.w, 0.f);
    *(half4v*)(&sHa[c * PITCH + nt * 16 + q * 4]) = h0;
  }
  __syncthreads();
  // fo2 (K=128), transposed-C
  half8 g1[4];
#pragma unroll
  for (int ks = 0; ks < 4; ks++)
    g1[ks] = *(const half8*)(&sHa[c * PITCH + ks * 32 + q * 8]);
#pragma unroll
  for (int nt2 = 0; nt2 < 2; nt2++) {
    int nt = wv * 2 + nt2;
    floatx4 a0 = {0.f, 0.f, 0.f, 0.f};
#pragma unroll
    for (int ks = 0; ks < 4; ks++) {
      half8 wf = *(const half8*)(&WT[OFF_FO2 + ((nt * 4 + ks) << 9) + (lane << 3)]);
      a0 = MFMA(wf, g1[ks], a0);
    }
    float4 bb = *(const float4*)(&fo2_b[nt * 16 + q * 4]);
    half4v h0;
    h0[0] = (_Float16)fmaxf(a0[0] + bb.x, 0.f);
    h0[1] = (_Float16)fmaxf(a0[1] + bb.y, 0.f);
    h0[2] = (_Float16)fmaxf(a0[2] + bb.z, 0.f);
    h0[3] = (_Float16)fmaxf(a0[3] + bb.w, 0.f);
    *(half4v*)(&sHb[c * PITCH + nt * 16 + q * 4]) = h0;
  }
  __syncthreads();
  // fo3 (N=64): wave owns 16 cols; pool over the 8 real nodes
  half8 g2[4];
#pragma unroll
  for (int ks = 0; ks < 4; ks++)
    g2[ks] = *(const half8*)(&sHb[c * PITCH + ks * 32 + q * 8]);
  floatx4 e0 = {0.f, 0.f, 0.f, 0.f};
#pragma unroll
  for (int ks = 0; ks < 4; ks++) {
    half8 wf = *(const half8*)(&WT[OFF_FO3 + ((wv * 4 + ks) << 9) + (lane << 3)]);
    e0 = MFMA(g2[ks], wf, e0);
  }
  float bb3 = fo3_b[wv * 16 + c];
  float s = 0.f;
  if (q < 2) {
#pragma unroll
    for (int rg = 0; rg < 4; rg++) s += fmaxf(e0[rg] + bb3, 0.f);
  }
  s += __shfl_xor(s, 16);
  if (lane < 16) sPool[wv * 16 + c] = s;
  __syncthreads();
  if (tid < NCLS) {
    float o = (r0 == 0) ? fc_b[tid] : 0.f;
#pragma unroll
    for (int d = 0; d < 64; d++) o += sPool[d] * fc_w[d * NCLS + tid];
    atomicAdd(&out[b * NCLS + tid], o);
  }
}

extern "C" void kernel_launch(void* const* d_in, const int* in_sizes, int n_in,
                              void* d_out, int out_size, void* d_ws, size_t ws_size,
                              hipStream_t stream) {
  const float* x = (const float*)d_in[0];
  const float* y = (const float*)d_in[1];
  const float* fr1_w = (const float*)d_in[2];  const float* fr1_b = (const float*)d_in[3];
  const float* fr2_w = (const float*)d_in[4];  const float* fr2_b = (const float*)d_in[5];
  const float* fr3_w = (const float*)d_in[6];  const float* fr3_b = (const float*)d_in[7];
  const float* fr1pv_w = (const float*)d_in[8];  const float* fr1pv_b = (const float*)d_in[9];
  const float* fr2pv_w = (const float*)d_in[10]; const float* fr2pv_b = (const float*)d_in[11];
  const float* fr3pv_w = (const float*)d_in[12]; const float* fr3pv_b = (const float*)d_in[13];
  const float* fo1_w = (const float*)d_in[14];  const float* fo1_b = (const float*)d_in[15];
  const float* fo2_w = (const float*)d_in[16];  const float* fo2_b = (const float*)d_in[17];
  const float* fo3_w = (const float*)d_in[18];  const float* fo3_b = (const float*)d_in[19];
  const float* fc_w = (const float*)d_in[20];   const float* fc_b = (const float*)d_in[21];

  char* ws = (char*)d_ws;
  _Float16* A1h   = (_Float16*)(ws);                 // [128][64][128] fp16, 2 MB (bias folded)
  _Float16* B1h   = (_Float16*)(ws + (2u << 20));    // 2 MB
  _Float16* A1pvh = (_Float16*)(ws + (4u << 20));    // 2 MB (bias folded)
  _Float16* B1pvh = (_Float16*)(ws + (6u << 20));    // [128][14][128] fp16
  _Float16* WT    = (_Float16*)(ws + (7u << 20));    // frag-major fp16 weights (~200 KB)

  k0_prep<<<520, 256, 0, stream>>>(x, y, fr1_w, fr1_b, fr1pv_w, fr1pv_b,
                                   fr2_w, fr3_w, fr2pv_w, fr3pv_w,
                                   fo1_w, fo2_w, fo3_w,
                                   A1h, B1h, A1pvh, B1pvh, WT, (float*)d_out);
  mega<<<NB * 8, 256, 0, stream>>>(A1h, B1h, A1pvh, B1pvh, x,
                                   fr2_b, fr3_b, fr2pv_b, fr3pv_b,
                                   fo1_b, fo2_b, fo3_b, fc_w, fc_b,
                                   WT, (float*)d_out);
}